// Round 4
// baseline (4493.514 us; speedup 1.0000x reference)
//
#include <hip/hip_runtime.h>
#include <hip/hip_bf16.h>
#include <cmath>

// ---------------------------------------------------------------------------
// MultiHeadMamba6mer: 2-layer Mamba2 + 4 classification heads.
// B=32 L=512 D_MODEL=384 D_INNER=768 D_STATE=64 D_CONV=4 HEADDIM=48 NHEADS=16
// D_IN_PROJ=1680 CONV_DIM=896. Output (32, 38667) FLOAT32 (reference dtype).
// Input float dtype AUTO-DETECTED at runtime (fp32 vs bf16) from ln_w (== ones):
//   first u32 == 0x3F800000 -> fp32 ; 0x3F803F80 (two bf16 1.0s) -> bf16.
//   (Round-3 evidence: inputs are fp32 storage, bf16-rounded values.)
// Internal compute: fp32 workspace (~221 MB).
// ---------------------------------------------------------------------------

#define B_SZ 32
#define L_SZ 512
#define DMODEL 384
#define DINNER 768
#define DSTATE 64
#define HEADDIM 48
#define NHEADS 16
#define DINPROJ 1680
#define CONVDIM 896
#define ROWS (B_SZ * L_SZ)          // 16384
#define OUT_STRIDE 38667

typedef __hip_bfloat16 bf16;

// dtype-dispatched weight load (element index). Explicit branch so the
// compiler cannot speculate the wrong-dtype load.
__device__ __forceinline__ float ldw(const void* p, size_t i, bool isb) {
    if (isb) return __bfloat162float(((const bf16*)p)[i]);
    else     return ((const float*)p)[i];
}

// ---------------- dtype detect: flag = 1 if bf16, 0 if fp32 ----------------
__global__ void detect_kernel(const void* __restrict__ ln_w, int* __restrict__ flag) {
    unsigned u = *(const unsigned*)ln_w;
    *flag = (u == 0x3F800000u) ? 0 : 1;
}

// ---------------- embed: resid[r,d] = emb[tok[r], d] ----------------
__global__ void embed_kernel(const int* __restrict__ tok,
                             const void* __restrict__ emb,
                             float* __restrict__ resid,
                             const int* __restrict__ dflag) {
    bool isb = (*dflag != 0);
    int r = blockIdx.x, d = threadIdx.x;                  // block 384
    resid[(size_t)r * DMODEL + d] = ldw(emb, (size_t)tok[r] * DMODEL + d, isb);
}

// ---------------- layernorm (one wave per row) ----------------
__global__ void layernorm_off(const float* __restrict__ x,
                              const void* __restrict__ w,
                              const void* __restrict__ b, long off,
                              float* __restrict__ out, int D,
                              const int* __restrict__ dflag) {
    bool isb = (*dflag != 0);
    int row = blockIdx.x, lane = threadIdx.x;             // block 64
    const float* xr = x + (size_t)row * D;
    float s = 0.f, s2 = 0.f;
    for (int d = lane; d < D; d += 64) { float v = xr[d]; s += v; s2 += v * v; }
    #pragma unroll
    for (int o = 32; o; o >>= 1) { s += __shfl_xor(s, o); s2 += __shfl_xor(s2, o); }
    float mu = s / D;
    float var = s2 / D - mu * mu;
    float rinv = rsqrtf(var + 1e-5f);
    for (int d = lane; d < D; d += 64)
        out[(size_t)row * D + d] =
            (xr[d] - mu) * rinv * ldw(w, off + d, isb) + ldw(b, off + d, isb);
}

// ---------------- tiled fp32 GEMM: C[M,N] = A[M,K](lda) * W[K,N] (+Cadd) ------
// block 256, 64x64 tile, 4x4 microtile. M%64==0, K%16==0, N%4==0 assumed.
__global__ void gemm_off(const float* __restrict__ A, int lda,
                         const void* __restrict__ Bw, long boff,
                         float* __restrict__ C, int ldc,
                         const float* __restrict__ Cadd,
                         int M, int N, int K,
                         const int* __restrict__ dflag) {
    bool isb = (*dflag != 0);
    __shared__ float As[16][68];
    __shared__ float Bs[16][68];
    const int bm = blockIdx.y * 64;
    const int bn = blockIdx.x * 64;
    const int tid = threadIdx.x;
    const int tx = tid & 15;      // n group
    const int ty = tid >> 4;      // m group
    float acc[4][4] = {};
    for (int k0 = 0; k0 < K; k0 += 16) {
        #pragma unroll
        for (int i = 0; i < 4; ++i) {
            int e = tid + 256 * i;                        // 0..1023
            int m = e >> 4, k = e & 15;
            As[k][m] = A[(size_t)(bm + m) * lda + k0 + k];
            int n = e & 63, kk = e >> 6;
            int gn = bn + n;
            Bs[kk][n] = (gn < N) ? ldw(Bw, boff + (size_t)(k0 + kk) * N + gn, isb) : 0.f;
        }
        __syncthreads();
        #pragma unroll
        for (int k = 0; k < 16; ++k) {
            float4 av = *(const float4*)&As[k][ty * 4];
            float4 bv = *(const float4*)&Bs[k][tx * 4];
            float a[4] = {av.x, av.y, av.z, av.w};
            float b4[4] = {bv.x, bv.y, bv.z, bv.w};
            #pragma unroll
            for (int i = 0; i < 4; ++i)
                #pragma unroll
                for (int j = 0; j < 4; ++j)
                    acc[i][j] += a[i] * b4[j];
        }
        __syncthreads();
    }
    #pragma unroll
    for (int i = 0; i < 4; ++i) {
        int m = bm + ty * 4 + i;
        int n = bn + tx * 4;
        if (n < N) {
            size_t idx = (size_t)m * ldc + n;
            float4 v = make_float4(acc[i][0], acc[i][1], acc[i][2], acc[i][3]);
            if (Cadd) {
                float4 c0 = *(const float4*)&Cadd[idx];
                v.x += c0.x; v.y += c0.y; v.z += c0.z; v.w += c0.w;
            }
            *(float4*)&C[idx] = v;
        }
    }
}

// ---------------- causal depthwise conv(4) + bias + SiLU ----------------
__global__ void conv_silu_off(const float* __restrict__ zx,
                              const void* __restrict__ cw,
                              const void* __restrict__ cb,
                              long cwoff, long cboff,
                              float* __restrict__ out,
                              const int* __restrict__ dflag) {
    bool isb = (*dflag != 0);
    int c = blockIdx.x * 128 + threadIdx.x;               // < 896 (7*128)
    int r = blockIdx.y;                                   // b*512 + l
    int l = r & (L_SZ - 1);
    float acc = ldw(cb, cboff + c, isb);
    #pragma unroll
    for (int k = 0; k < 4; ++k) {
        int lsrc = l + k - 3;
        if (lsrc >= 0)
            acc += zx[(size_t)(r + k - 3) * DINPROJ + DINNER + c] *
                   ldw(cw, cwoff + c * 4 + k, isb);
    }
    out[(size_t)r * CONVDIM + c] = acc / (1.f + expf(-acc));
}

// ---------------- dt = softplus(raw + bias); dA = exp(-exp(alog)*dt) ----------
__global__ void dt_off(const float* __restrict__ zx,
                       const void* __restrict__ dtb,
                       const void* __restrict__ alog, long hoff,
                       float* __restrict__ dtout, float* __restrict__ dAout,
                       const int* __restrict__ dflag) {
    bool isb = (*dflag != 0);
    int idx = blockIdx.x * 256 + threadIdx.x;             // < ROWS*NHEADS
    int r = idx >> 4, h = idx & 15;
    float x = zx[(size_t)r * DINPROJ + (DINPROJ - NHEADS) + h] + ldw(dtb, hoff + h, isb);
    float sp = (x > 20.f) ? x : log1pf(expf(x));
    float A = expf(ldw(alog, hoff + h, isb));
    dtout[idx] = sp;
    dAout[idx] = expf(-A * sp);
}

// ---------------- sequential SSM scan, one wave per (b, head) ----------------
// lane p holds state[p][0..63] (p<48); y overwrites conv-x columns of its head.
__global__ void scan_off(float* __restrict__ conv,
                         const float* __restrict__ dtg,
                         const float* __restrict__ dAg,
                         const void* __restrict__ Dsk, long hoff,
                         const int* __restrict__ dflag) {
    bool isb = (*dflag != 0);
    int b = blockIdx.x >> 4, h = blockIdx.x & 15;
    int lane = threadIdx.x;                               // block 64 (one wave)
    __shared__ __align__(16) float sB[64];
    __shared__ __align__(16) float sC[64];
    float st[64];
    #pragma unroll
    for (int n = 0; n < 64; ++n) st[n] = 0.f;
    float dskip = ldw(Dsk, hoff + h, isb);
    float* base = conv + (size_t)b * L_SZ * CONVDIM;
    for (int t = 0; t < L_SZ; ++t) {
        float* row = base + (size_t)t * CONVDIM;
        float xv = (lane < HEADDIM) ? row[h * HEADDIM + lane] : 0.f;
        sB[lane] = row[DINNER + lane];
        sC[lane] = row[DINNER + DSTATE + lane];
        int ri = (b * L_SZ + t) * NHEADS + h;
        float dtv = dtg[ri], dAv = dAg[ri];
        __syncthreads();
        float coef = dtv * xv;
        float a0 = 0.f, a1 = 0.f, a2 = 0.f, a3 = 0.f;
        #pragma unroll
        for (int n = 0; n < 64; n += 4) {
            float4 Bq = *(const float4*)&sB[n];
            float4 Cq = *(const float4*)&sC[n];
            st[n + 0] = st[n + 0] * dAv + coef * Bq.x; a0 += st[n + 0] * Cq.x;
            st[n + 1] = st[n + 1] * dAv + coef * Bq.y; a1 += st[n + 1] * Cq.y;
            st[n + 2] = st[n + 2] * dAv + coef * Bq.z; a2 += st[n + 2] * Cq.z;
            st[n + 3] = st[n + 3] * dAv + coef * Bq.w; a3 += st[n + 3] * Cq.w;
        }
        float y = (a0 + a1) + (a2 + a3) + dskip * xv;
        __syncthreads();                                  // WAR guard
        if (lane < HEADDIM) row[h * HEADDIM + lane] = y;
    }
}

// ---------------- gated RMSNorm: y = (y*silu(z)) * rsqrt(mean(y^2)+eps) * gw --
__global__ void gated_off(float* __restrict__ y,          // conv buf rows (896)
                          const float* __restrict__ zx,
                          const void* __restrict__ gw, long goff,
                          const int* __restrict__ dflag) {
    bool isb = (*dflag != 0);
    int row = blockIdx.x, tid = threadIdx.x;              // block 256
    float* yr = y + (size_t)row * CONVDIM;
    const float* zr = zx + (size_t)row * DINPROJ;
    float g[3], s2 = 0.f;
    #pragma unroll
    for (int i = 0; i < 3; ++i) {
        int d = tid + 256 * i;
        float z = zr[d];
        float sz = z / (1.f + expf(-z));
        float v = yr[d] * sz;
        g[i] = v; s2 += v * v;
    }
    #pragma unroll
    for (int o = 32; o; o >>= 1) s2 += __shfl_xor(s2, o);
    __shared__ float red[4];
    if ((tid & 63) == 0) red[tid >> 6] = s2;
    __syncthreads();
    s2 = red[0] + red[1] + red[2] + red[3];
    float rinv = rsqrtf(s2 / (float)DINNER + 1e-5f);
    #pragma unroll
    for (int i = 0; i < 3; ++i) {
        int d = tid + 256 * i;
        yr[d] = g[i] * rinv * ldw(gw, goff + d, isb);
    }
}

// ---------------- mean over L ----------------
__global__ void pool_kernel(const float* __restrict__ h, float* __restrict__ feat0) {
    int b = blockIdx.x, d = threadIdx.x;                  // block 384
    float s = 0.f;
    for (int l = 0; l < L_SZ; ++l) s += h[((size_t)b * L_SZ + l) * DMODEL + d];
    feat0[b * DMODEL + d] = s * (1.f / L_SZ);
}

// ---------------- head GEMV: out[b, off+j] = feat[b,:] . W[:,j] + bias[j] -----
// Output buffer is FLOAT32 (reference output dtype).
__global__ void head_kernel(const float* __restrict__ feat,
                            const void* __restrict__ W,
                            const void* __restrict__ bias,
                            float* __restrict__ out, int N, int off,
                            const int* __restrict__ dflag) {
    bool isb = (*dflag != 0);
    __shared__ float sf[DMODEL];
    int b = blockIdx.y;
    for (int i = threadIdx.x; i < DMODEL; i += 256) sf[i] = feat[b * DMODEL + i];
    __syncthreads();
    int j = blockIdx.x * 256 + threadIdx.x;
    if (j < N) {
        float acc = ldw(bias, j, isb);
        if (isb) {
            const bf16* Wb = (const bf16*)W;
            for (int k = 0; k < DMODEL; ++k)
                acc += sf[k] * __bfloat162float(Wb[(size_t)k * N + j]);
        } else {
            const float* Wf = (const float*)W;
            for (int k = 0; k < DMODEL; ++k)
                acc += sf[k] * Wf[(size_t)k * N + j];
        }
        out[(size_t)b * OUT_STRIDE + off + j] = acc;
    }
}

// ---------------------------------------------------------------------------
extern "C" void kernel_launch(void* const* d_in, const int* in_sizes, int n_in,
                              void* d_out, int out_size, void* d_ws, size_t ws_size,
                              hipStream_t stream) {
    const int*  tokens   = (const int*)d_in[0];
    const void* emb      = d_in[1];
    const void* ln_w     = d_in[2];
    const void* ln_b     = d_in[3];
    const void* in_proj  = d_in[4];
    const void* conv_w   = d_in[5];
    const void* conv_b   = d_in[6];
    const void* dt_bias  = d_in[7];
    const void* A_log    = d_in[8];
    const void* Dp       = d_in[9];
    const void* gnorm_w  = d_in[10];
    const void* out_proj = d_in[11];
    const void* normf_w  = d_in[12];
    const void* normf_b  = d_in[13];
    const void* pln_w    = d_in[14];
    const void* pln_b    = d_in[15];
    const void* order_w  = d_in[16];
    const void* order_b  = d_in[17];
    const void* family_w = d_in[18];
    const void* family_b = d_in[19];
    const void* genus_w  = d_in[20];
    const void* genus_b  = d_in[21];
    const void* species_w= d_in[22];
    const void* species_b= d_in[23];
    float* out = (float*)d_out;

    // fp32 workspace layout (~221 MB)
    float* ws    = (float*)d_ws;
    float* resid = ws;                                   // 16384*384
    float* hbuf  = resid + (size_t)ROWS * DMODEL;        // 16384*384
    float* zx    = hbuf  + (size_t)ROWS * DMODEL;        // 16384*1680
    float* convb = zx    + (size_t)ROWS * DINPROJ;       // 16384*896
    float* dtb_  = convb + (size_t)ROWS * CONVDIM;       // 16384*16
    float* dAb   = dtb_  + (size_t)ROWS * NHEADS;        // 16384*16
    float* feat0 = dAb   + (size_t)ROWS * NHEADS;        // 32*384
    float* feat  = feat0 + (size_t)B_SZ * DMODEL;        // 32*384
    int*   dflag = (int*)(feat + (size_t)B_SZ * DMODEL);

    detect_kernel<<<1, 1, 0, stream>>>(ln_w, dflag);
    embed_kernel<<<ROWS, DMODEL, 0, stream>>>(tokens, emb, resid, dflag);

    for (int l = 0; l < 2; ++l) {
        layernorm_off<<<ROWS, 64, 0, stream>>>(resid, ln_w, ln_b,
            (long)l * DMODEL, hbuf, DMODEL, dflag);
        // zxbcdt = h @ W_in   (16384 x 384 -> 1680)
        gemm_off<<<dim3((DINPROJ + 63) / 64, ROWS / 64), 256, 0, stream>>>(
            hbuf, DMODEL, in_proj, (long)l * DMODEL * DINPROJ,
            zx, DINPROJ, nullptr, ROWS, DINPROJ, DMODEL, dflag);
        conv_silu_off<<<dim3(7, ROWS), 128, 0, stream>>>(
            zx, conv_w, conv_b, (long)l * CONVDIM * 4, (long)l * CONVDIM,
            convb, dflag);
        dt_off<<<(ROWS * NHEADS) / 256, 256, 0, stream>>>(
            zx, dt_bias, A_log, (long)l * NHEADS, dtb_, dAb, dflag);
        scan_off<<<B_SZ * NHEADS, 64, 0, stream>>>(convb, dtb_, dAb, Dp,
            (long)l * NHEADS, dflag);
        gated_off<<<ROWS, 256, 0, stream>>>(convb, zx, gnorm_w,
            (long)l * DINNER, dflag);
        // resid += y @ W_out  (16384 x 768 -> 384), y rows strided by 896
        gemm_off<<<dim3(DMODEL / 64, ROWS / 64), 256, 0, stream>>>(
            convb, CONVDIM, out_proj, (long)l * DINNER * DMODEL,
            resid, DMODEL, resid, ROWS, DMODEL, DINNER, dflag);
    }

    layernorm_off<<<ROWS, 64, 0, stream>>>(resid, normf_w, normf_b, 0L,
                                           hbuf, DMODEL, dflag);
    pool_kernel<<<B_SZ, DMODEL, 0, stream>>>(hbuf, feat0);
    layernorm_off<<<B_SZ, 64, 0, stream>>>(feat0, pln_w, pln_b, 0L,
                                           feat, DMODEL, dflag);

    head_kernel<<<dim3(1, B_SZ), 256, 0, stream>>>(feat, order_w, order_b, out, 60, 0, dflag);
    head_kernel<<<dim3(2, B_SZ), 256, 0, stream>>>(feat, family_w, family_b, out, 427, 60, dflag);
    head_kernel<<<dim3(56, B_SZ), 256, 0, stream>>>(feat, genus_w, genus_b, out, 14216, 487, dflag);
    head_kernel<<<dim3(94, B_SZ), 256, 0, stream>>>(feat, species_w, species_b, out, 23964, 14703, dflag);
}

// Round 5
// 2777.580 us; speedup vs baseline: 1.6178x; 1.6178x over previous
//
#include <hip/hip_runtime.h>
#include <hip/hip_bf16.h>
#include <cmath>

// ---------------------------------------------------------------------------
// MultiHeadMamba6mer: 2-layer Mamba2 + 4 classification heads.
// B=32 L=512 D_MODEL=384 D_INNER=768 D_STATE=64 D_CONV=4 HEADDIM=48 NHEADS=16
// D_IN_PROJ=1680 CONV_DIM=896. Output (32, 38667) FLOAT32 (reference dtype).
// Input float dtype AUTO-DETECTED (fp32 vs bf16) from ln_w (== ones).
// R4: scan rewritten with LDS chunk staging (Tc=64) — was latency-bound at
//     1480 us/dispatch (VALUBusy 5.4%, occupancy 5.9%).
// ---------------------------------------------------------------------------

#define B_SZ 32
#define L_SZ 512
#define DMODEL 384
#define DINNER 768
#define DSTATE 64
#define HEADDIM 48
#define NHEADS 16
#define DINPROJ 1680
#define CONVDIM 896
#define ROWS (B_SZ * L_SZ)          // 16384
#define OUT_STRIDE 38667
#define TC 64                        // scan chunk length

typedef __hip_bfloat16 bf16;

__device__ __forceinline__ float ldw(const void* p, size_t i, bool isb) {
    if (isb) return __bfloat162float(((const bf16*)p)[i]);
    else     return ((const float*)p)[i];
}

// ---------------- dtype detect: flag = 1 if bf16, 0 if fp32 ----------------
__global__ void detect_kernel(const void* __restrict__ ln_w, int* __restrict__ flag) {
    unsigned u = *(const unsigned*)ln_w;
    *flag = (u == 0x3F800000u) ? 0 : 1;
}

// ---------------- embed ----------------
__global__ void embed_kernel(const int* __restrict__ tok,
                             const void* __restrict__ emb,
                             float* __restrict__ resid,
                             const int* __restrict__ dflag) {
    bool isb = (*dflag != 0);
    int r = blockIdx.x, d = threadIdx.x;                  // block 384
    resid[(size_t)r * DMODEL + d] = ldw(emb, (size_t)tok[r] * DMODEL + d, isb);
}

// ---------------- layernorm (one wave per row) ----------------
__global__ void layernorm_off(const float* __restrict__ x,
                              const void* __restrict__ w,
                              const void* __restrict__ b, long off,
                              float* __restrict__ out, int D,
                              const int* __restrict__ dflag) {
    bool isb = (*dflag != 0);
    int row = blockIdx.x, lane = threadIdx.x;             // block 64
    const float* xr = x + (size_t)row * D;
    float s = 0.f, s2 = 0.f;
    for (int d = lane; d < D; d += 64) { float v = xr[d]; s += v; s2 += v * v; }
    #pragma unroll
    for (int o = 32; o; o >>= 1) { s += __shfl_xor(s, o); s2 += __shfl_xor(s2, o); }
    float mu = s / D;
    float var = s2 / D - mu * mu;
    float rinv = rsqrtf(var + 1e-5f);
    for (int d = lane; d < D; d += 64)
        out[(size_t)row * D + d] =
            (xr[d] - mu) * rinv * ldw(w, off + d, isb) + ldw(b, off + d, isb);
}

// ---------------- tiled fp32 GEMM: C[M,N] = A[M,K](lda) * W[K,N] (+Cadd) ------
__global__ void gemm_off(const float* __restrict__ A, int lda,
                         const void* __restrict__ Bw, long boff,
                         float* __restrict__ C, int ldc,
                         const float* __restrict__ Cadd,
                         int M, int N, int K,
                         const int* __restrict__ dflag) {
    bool isb = (*dflag != 0);
    __shared__ float As[16][68];
    __shared__ float Bs[16][68];
    const int bm = blockIdx.y * 64;
    const int bn = blockIdx.x * 64;
    const int tid = threadIdx.x;
    const int tx = tid & 15;
    const int ty = tid >> 4;
    float acc[4][4] = {};
    for (int k0 = 0; k0 < K; k0 += 16) {
        #pragma unroll
        for (int i = 0; i < 4; ++i) {
            int e = tid + 256 * i;
            int m = e >> 4, k = e & 15;
            As[k][m] = A[(size_t)(bm + m) * lda + k0 + k];
            int n = e & 63, kk = e >> 6;
            int gn = bn + n;
            Bs[kk][n] = (gn < N) ? ldw(Bw, boff + (size_t)(k0 + kk) * N + gn, isb) : 0.f;
        }
        __syncthreads();
        #pragma unroll
        for (int k = 0; k < 16; ++k) {
            float4 av = *(const float4*)&As[k][ty * 4];
            float4 bv = *(const float4*)&Bs[k][tx * 4];
            float a[4] = {av.x, av.y, av.z, av.w};
            float b4[4] = {bv.x, bv.y, bv.z, bv.w};
            #pragma unroll
            for (int i = 0; i < 4; ++i)
                #pragma unroll
                for (int j = 0; j < 4; ++j)
                    acc[i][j] += a[i] * b4[j];
        }
        __syncthreads();
    }
    #pragma unroll
    for (int i = 0; i < 4; ++i) {
        int m = bm + ty * 4 + i;
        int n = bn + tx * 4;
        if (n < N) {
            size_t idx = (size_t)m * ldc + n;
            float4 v = make_float4(acc[i][0], acc[i][1], acc[i][2], acc[i][3]);
            if (Cadd) {
                float4 c0 = *(const float4*)&Cadd[idx];
                v.x += c0.x; v.y += c0.y; v.z += c0.z; v.w += c0.w;
            }
            *(float4*)&C[idx] = v;
        }
    }
}

// ---------------- causal depthwise conv(4) + bias + SiLU ----------------
__global__ void conv_silu_off(const float* __restrict__ zx,
                              const void* __restrict__ cw,
                              const void* __restrict__ cb,
                              long cwoff, long cboff,
                              float* __restrict__ out,
                              const int* __restrict__ dflag) {
    bool isb = (*dflag != 0);
    int c = blockIdx.x * 128 + threadIdx.x;               // < 896 (7*128)
    int r = blockIdx.y;                                   // b*512 + l
    int l = r & (L_SZ - 1);
    float acc = ldw(cb, cboff + c, isb);
    #pragma unroll
    for (int k = 0; k < 4; ++k) {
        int lsrc = l + k - 3;
        if (lsrc >= 0)
            acc += zx[(size_t)(r + k - 3) * DINPROJ + DINNER + c] *
                   ldw(cw, cwoff + c * 4 + k, isb);
    }
    out[(size_t)r * CONVDIM + c] = acc / (1.f + expf(-acc));
}

// ---------------- dt = softplus(raw + bias); dA = exp(-exp(alog)*dt) ----------
__global__ void dt_off(const float* __restrict__ zx,
                       const void* __restrict__ dtb,
                       const void* __restrict__ alog, long hoff,
                       float* __restrict__ dtout, float* __restrict__ dAout,
                       const int* __restrict__ dflag) {
    bool isb = (*dflag != 0);
    int idx = blockIdx.x * 256 + threadIdx.x;             // < ROWS*NHEADS
    int r = idx >> 4, h = idx & 15;
    float x = zx[(size_t)r * DINPROJ + (DINPROJ - NHEADS) + h] + ldw(dtb, hoff + h, isb);
    float sp = (x > 20.f) ? x : log1pf(expf(x));
    float A = expf(ldw(alog, hoff + h, isb));
    dtout[idx] = sp;
    dAout[idx] = expf(-A * sp);
}

// ---------------- SSM scan, LDS chunk-staged. One wave per (b, head). --------
// Lane p holds state[p][0..63] in 64 VGPRs. Per chunk of TC=64 timesteps:
// stage x/B/C/dt/dA with ~194 independent coalesced loads (latency amortized),
// then run the serial recurrence out of LDS. y overwrites conv-x in place
// (only this head's columns; B/C columns 768..895 are never written).
__global__ void scan_off(float* __restrict__ conv,
                         const float* __restrict__ dtg,
                         const float* __restrict__ dAg,
                         const void* __restrict__ Dsk, long hoff,
                         const int* __restrict__ dflag) {
    bool isb = (*dflag != 0);
    int b = blockIdx.x >> 4, h = blockIdx.x & 15;
    int lane = threadIdx.x;                               // block 64 (one wave)
    __shared__ float sX[TC][HEADDIM];                     // 12 KB
    __shared__ __align__(16) float sB[TC][DSTATE];        // 16 KB
    __shared__ __align__(16) float sC[TC][DSTATE];        // 16 KB
    __shared__ float sdt[TC];
    __shared__ float sdA[TC];
    float st[64];
    #pragma unroll
    for (int n = 0; n < 64; ++n) st[n] = 0.f;
    float dskip = ldw(Dsk, hoff + h, isb);
    float* base = conv + (size_t)b * L_SZ * CONVDIM;

    for (int c0 = 0; c0 < L_SZ; c0 += TC) {
        // ---- stage chunk: independent loads, deep MLP ----
        sdt[lane] = dtg[((size_t)(b * L_SZ + c0 + lane)) * NHEADS + h];
        sdA[lane] = dAg[((size_t)(b * L_SZ + c0 + lane)) * NHEADS + h];
        #pragma unroll 8
        for (int tt = 0; tt < TC; ++tt) {
            const float* row = base + (size_t)(c0 + tt) * CONVDIM;
            if (lane < HEADDIM) sX[tt][lane] = row[h * HEADDIM + lane];
            sB[tt][lane] = row[DINNER + lane];
            sC[tt][lane] = row[DINNER + DSTATE + lane];
        }
        __syncthreads();
        // ---- serial recurrence out of LDS ----
        for (int tt = 0; tt < TC; ++tt) {
            float xv = (lane < HEADDIM) ? sX[tt][lane] : 0.f;
            float dAv = sdA[tt];
            float coef = sdt[tt] * xv;
            float a0 = 0.f, a1 = 0.f, a2 = 0.f, a3 = 0.f;
            #pragma unroll
            for (int n = 0; n < 64; n += 4) {
                float4 Bq = *(const float4*)&sB[tt][n];
                float4 Cq = *(const float4*)&sC[tt][n];
                st[n + 0] = st[n + 0] * dAv + coef * Bq.x; a0 += st[n + 0] * Cq.x;
                st[n + 1] = st[n + 1] * dAv + coef * Bq.y; a1 += st[n + 1] * Cq.y;
                st[n + 2] = st[n + 2] * dAv + coef * Bq.z; a2 += st[n + 2] * Cq.z;
                st[n + 3] = st[n + 3] * dAv + coef * Bq.w; a3 += st[n + 3] * Cq.w;
            }
            float y = (a0 + a1) + (a2 + a3) + dskip * xv;
            if (lane < HEADDIM)
                base[(size_t)(c0 + tt) * CONVDIM + h * HEADDIM + lane] = y;
        }
        __syncthreads();                                  // LDS reuse guard
    }
}

// ---------------- gated RMSNorm ----------------
__global__ void gated_off(float* __restrict__ y,          // conv buf rows (896)
                          const float* __restrict__ zx,
                          const void* __restrict__ gw, long goff,
                          const int* __restrict__ dflag) {
    bool isb = (*dflag != 0);
    int row = blockIdx.x, tid = threadIdx.x;              // block 256
    float* yr = y + (size_t)row * CONVDIM;
    const float* zr = zx + (size_t)row * DINPROJ;
    float g[3], s2 = 0.f;
    #pragma unroll
    for (int i = 0; i < 3; ++i) {
        int d = tid + 256 * i;
        float z = zr[d];
        float sz = z / (1.f + expf(-z));
        float v = yr[d] * sz;
        g[i] = v; s2 += v * v;
    }
    #pragma unroll
    for (int o = 32; o; o >>= 1) s2 += __shfl_xor(s2, o);
    __shared__ float red[4];
    if ((tid & 63) == 0) red[tid >> 6] = s2;
    __syncthreads();
    s2 = red[0] + red[1] + red[2] + red[3];
    float rinv = rsqrtf(s2 / (float)DINNER + 1e-5f);
    #pragma unroll
    for (int i = 0; i < 3; ++i) {
        int d = tid + 256 * i;
        yr[d] = g[i] * rinv * ldw(gw, goff + d, isb);
    }
}

// ---------------- mean over L ----------------
__global__ void pool_kernel(const float* __restrict__ h, float* __restrict__ feat0) {
    int b = blockIdx.x, d = threadIdx.x;                  // block 384
    float s = 0.f;
    for (int l = 0; l < L_SZ; ++l) s += h[((size_t)b * L_SZ + l) * DMODEL + d];
    feat0[b * DMODEL + d] = s * (1.f / L_SZ);
}

// ---------------- head GEMV (fp32 output) ----------------
__global__ void head_kernel(const float* __restrict__ feat,
                            const void* __restrict__ W,
                            const void* __restrict__ bias,
                            float* __restrict__ out, int N, int off,
                            const int* __restrict__ dflag) {
    bool isb = (*dflag != 0);
    __shared__ float sf[DMODEL];
    int b = blockIdx.y;
    for (int i = threadIdx.x; i < DMODEL; i += 256) sf[i] = feat[b * DMODEL + i];
    __syncthreads();
    int j = blockIdx.x * 256 + threadIdx.x;
    if (j < N) {
        float acc = ldw(bias, j, isb);
        if (isb) {
            const bf16* Wb = (const bf16*)W;
            for (int k = 0; k < DMODEL; ++k)
                acc += sf[k] * __bfloat162float(Wb[(size_t)k * N + j]);
        } else {
            const float* Wf = (const float*)W;
            for (int k = 0; k < DMODEL; ++k)
                acc += sf[k] * Wf[(size_t)k * N + j];
        }
        out[(size_t)b * OUT_STRIDE + off + j] = acc;
    }
}

// ---------------------------------------------------------------------------
extern "C" void kernel_launch(void* const* d_in, const int* in_sizes, int n_in,
                              void* d_out, int out_size, void* d_ws, size_t ws_size,
                              hipStream_t stream) {
    const int*  tokens   = (const int*)d_in[0];
    const void* emb      = d_in[1];
    const void* ln_w     = d_in[2];
    const void* ln_b     = d_in[3];
    const void* in_proj  = d_in[4];
    const void* conv_w   = d_in[5];
    const void* conv_b   = d_in[6];
    const void* dt_bias  = d_in[7];
    const void* A_log    = d_in[8];
    const void* Dp       = d_in[9];
    const void* gnorm_w  = d_in[10];
    const void* out_proj = d_in[11];
    const void* normf_w  = d_in[12];
    const void* normf_b  = d_in[13];
    const void* pln_w    = d_in[14];
    const void* pln_b    = d_in[15];
    const void* order_w  = d_in[16];
    const void* order_b  = d_in[17];
    const void* family_w = d_in[18];
    const void* family_b = d_in[19];
    const void* genus_w  = d_in[20];
    const void* genus_b  = d_in[21];
    const void* species_w= d_in[22];
    const void* species_b= d_in[23];
    float* out = (float*)d_out;

    // fp32 workspace layout (~221 MB)
    float* ws    = (float*)d_ws;
    float* resid = ws;                                   // 16384*384
    float* hbuf  = resid + (size_t)ROWS * DMODEL;        // 16384*384
    float* zx    = hbuf  + (size_t)ROWS * DMODEL;        // 16384*1680
    float* convb = zx    + (size_t)ROWS * DINPROJ;       // 16384*896
    float* dtb_  = convb + (size_t)ROWS * CONVDIM;       // 16384*16
    float* dAb   = dtb_  + (size_t)ROWS * NHEADS;        // 16384*16
    float* feat0 = dAb   + (size_t)ROWS * NHEADS;        // 32*384
    float* feat  = feat0 + (size_t)B_SZ * DMODEL;        // 32*384
    int*   dflag = (int*)(feat + (size_t)B_SZ * DMODEL);

    detect_kernel<<<1, 1, 0, stream>>>(ln_w, dflag);
    embed_kernel<<<ROWS, DMODEL, 0, stream>>>(tokens, emb, resid, dflag);

    for (int l = 0; l < 2; ++l) {
        layernorm_off<<<ROWS, 64, 0, stream>>>(resid, ln_w, ln_b,
            (long)l * DMODEL, hbuf, DMODEL, dflag);
        // zxbcdt = h @ W_in   (16384 x 384 -> 1680)
        gemm_off<<<dim3((DINPROJ + 63) / 64, ROWS / 64), 256, 0, stream>>>(
            hbuf, DMODEL, in_proj, (long)l * DMODEL * DINPROJ,
            zx, DINPROJ, nullptr, ROWS, DINPROJ, DMODEL, dflag);
        conv_silu_off<<<dim3(7, ROWS), 128, 0, stream>>>(
            zx, conv_w, conv_b, (long)l * CONVDIM * 4, (long)l * CONVDIM,
            convb, dflag);
        dt_off<<<(ROWS * NHEADS) / 256, 256, 0, stream>>>(
            zx, dt_bias, A_log, (long)l * NHEADS, dtb_, dAb, dflag);
        scan_off<<<B_SZ * NHEADS, 64, 0, stream>>>(convb, dtb_, dAb, Dp,
            (long)l * NHEADS, dflag);
        gated_off<<<ROWS, 256, 0, stream>>>(convb, zx, gnorm_w,
            (long)l * DINNER, dflag);
        // resid += y @ W_out  (16384 x 768 -> 384), y rows strided by 896
        gemm_off<<<dim3(DMODEL / 64, ROWS / 64), 256, 0, stream>>>(
            convb, CONVDIM, out_proj, (long)l * DINNER * DMODEL,
            resid, DMODEL, resid, ROWS, DMODEL, DINNER, dflag);
    }

    layernorm_off<<<ROWS, 64, 0, stream>>>(resid, normf_w, normf_b, 0L,
                                           hbuf, DMODEL, dflag);
    pool_kernel<<<B_SZ, DMODEL, 0, stream>>>(hbuf, feat0);
    layernorm_off<<<B_SZ, 64, 0, stream>>>(feat0, pln_w, pln_b, 0L,
                                           feat, DMODEL, dflag);

    head_kernel<<<dim3(1, B_SZ), 256, 0, stream>>>(feat, order_w, order_b, out, 60, 0, dflag);
    head_kernel<<<dim3(2, B_SZ), 256, 0, stream>>>(feat, family_w, family_b, out, 427, 60, dflag);
    head_kernel<<<dim3(56, B_SZ), 256, 0, stream>>>(feat, genus_w, genus_b, out, 14216, 487, dflag);
    head_kernel<<<dim3(94, B_SZ), 256, 0, stream>>>(feat, species_w, species_b, out, 23964, 14703, dflag);
}